// Round 1
// baseline (4321.341 us; speedup 1.0000x reference)
//
#include <hip/hip_runtime.h>

// MoE FFN, top-2 of 8 experts. d_model=1024, d_inner=4096, T=8192 tokens.
// Strategy: routed (2/8 sparse) GEMMs on bf16 MFMA with hi/lo split precision
// (3 MFMAs: hh+hl+lh) for fp32-class accuracy on the 2.5PF matrix pipe.

#define DM 1024
#define DI 4096
#define NE 8
#define TOK 8192
#define MAXPE 8192           // max tokens routed to one expert (top-2 => <= TOK)
#define BM 128
#define BN 64
#define BK 64
#define MBMAX (MAXPE / BM)   // 64

typedef __attribute__((ext_vector_type(4))) float f32x4;
typedef __attribute__((ext_vector_type(8))) short bf16x8;
typedef __attribute__((ext_vector_type(4))) unsigned short u16x4;
typedef __attribute__((ext_vector_type(8))) unsigned short u16x8;

#define MFMA(a, b, c) __builtin_amdgcn_mfma_f32_16x16x32_bf16(a, b, c, 0, 0, 0)

__device__ __forceinline__ unsigned short bf16_rn(float f) {
    unsigned int u = __builtin_bit_cast(unsigned int, f);
    u += 0x7fffu + ((u >> 16) & 1u);          // round-to-nearest-even
    return (unsigned short)(u >> 16);
}
__device__ __forceinline__ float bf16_f(unsigned short h) {
    unsigned int u = ((unsigned int)h) << 16;
    return __builtin_bit_cast(float, u);
}

// ---------------------------------------------------------------------------
// Router: one wave per token. logits = x . rw^T + rb; top-2; renormalized
// weights (== softmax over the two top logits, identical to ref's
// softmax-all + topk + renorm). Atomic-append into per-expert pair lists.
// ---------------------------------------------------------------------------
__global__ __launch_bounds__(256) void router_kernel(
    const float* __restrict__ x, const float* __restrict__ rw,
    const float* __restrict__ rb,
    int* __restrict__ counts, int* __restrict__ tok_list,
    float* __restrict__ w_list)
{
    int t = blockIdx.x * 4 + (threadIdx.x >> 6);
    int lane = threadIdx.x & 63;
    const float* xr = x + (size_t)t * DM;
    float acc[NE];
#pragma unroll
    for (int e = 0; e < NE; ++e) acc[e] = 0.f;
    for (int i = lane; i < DM; i += 64) {
        float xv = xr[i];
#pragma unroll
        for (int e = 0; e < NE; ++e) acc[e] += xv * rw[e * DM + i];
    }
#pragma unroll
    for (int e = 0; e < NE; ++e) {
        float v = acc[e];
#pragma unroll
        for (int s = 32; s >= 1; s >>= 1) v += __shfl_xor(v, s, 64);
        acc[e] = v;
    }
    if (lane == 0) {
        float l0 = -3.4e38f, l1 = -3.4e38f;
        int i0 = 0, i1 = 0;
#pragma unroll
        for (int e = 0; e < NE; ++e) {
            float v = acc[e] + rb[e];
            if (v > l0) { l1 = l0; i1 = i0; l0 = v; i0 = e; }
            else if (v > l1) { l1 = v; i1 = e; }
        }
        float z = expf(l1 - l0);          // <= 1
        float w0 = 1.f / (1.f + z);
        float w1 = z / (1.f + z);
        int p0 = atomicAdd(&counts[i0], 1);
        tok_list[i0 * MAXPE + p0] = t; w_list[i0 * MAXPE + p0] = w0;
        int p1 = atomicAdd(&counts[i1], 1);
        tok_list[i1 * MAXPE + p1] = t; w_list[i1 * MAXPE + p1] = w1;
    }
}

__global__ void scan_kernel(const int* __restrict__ counts, int* __restrict__ offs) {
    if (threadIdx.x == 0) {
        int s = 0;
        for (int e = 0; e < NE; ++e) { offs[e] = s; s += counts[e]; }
    }
}

// ---------------------------------------------------------------------------
// Kernel A: for one expert m-tile and one 64-col slice of the d_inner chunk,
// compute G = X.gw^T and U = X.up^T (split-precision bf16 MFMA), then
// h = silu(g)*u, stored to H as bf16 hi/lo.
// ---------------------------------------------------------------------------
__global__ __launch_bounds__(256) void gateup_kernel(
    const float* __restrict__ x, const float* __restrict__ gw,
    const float* __restrict__ uw,
    const int* __restrict__ counts, const int* __restrict__ offs,
    const int* __restrict__ tok_list,
    unsigned short* __restrict__ Hhi, unsigned short* __restrict__ Hlo,
    int cb, int CH)
{
    const int e = blockIdx.x / MBMAX, mb = blockIdx.x % MBMAX;
    const int ne = counts[e];
    if (mb * BM >= ne) return;
    const int by = blockIdx.y;
    const int tid = threadIdx.x;

    __shared__ unsigned short Ahi[BM * BK], Alo[BM * BK];
    __shared__ unsigned short Bhi[2 * BN * BK], Blo[2 * BN * BK];
    __shared__ int s_tok[BM];

    if (tid < BM) {
        int r = mb * BM + tid;
        s_tok[tid] = (r < ne) ? tok_list[e * MAXPE + r] : -1;
    }

    const float* gbase = gw + (size_t)e * DI * DM + (size_t)(cb + by * BN) * DM;
    const float* ubase = uw + (size_t)e * DI * DM + (size_t)(cb + by * BN) * DM;

    const int lane = tid & 63, wv = tid >> 6;
    const int wm = wv >> 1, wn = wv & 1;
    const int lr = lane & 15, lk = lane >> 4;

    f32x4 accg[4][2], accu[4][2];
#pragma unroll
    for (int m = 0; m < 4; ++m)
#pragma unroll
        for (int n = 0; n < 2; ++n) { accg[m][n] = (f32x4)0.f; accu[m][n] = (f32x4)0.f; }

    __syncthreads();   // s_tok visible

    for (int kt = 0; kt < DM / BK; ++kt) {
        // ---- stage A (gathered X rows, f32 -> bf16 hi/lo, XOR-swizzled) ----
#pragma unroll
        for (int it = 0; it < 8; ++it) {
            int idx = it * 256 + tid;          // 0..2047
            int row = idx >> 4;                // 0..127
            int kq = (idx & 15) << 2;          // 0,4,..,60
            f32x4 v = (f32x4)0.f;
            int tok = s_tok[row];
            if (tok >= 0) v = *(const f32x4*)(x + (size_t)tok * DM + kt * BK + kq);
            u16x4 hi, lo;
#pragma unroll
            for (int j = 0; j < 4; ++j) {
                unsigned short h = bf16_rn(v[j]);
                hi[j] = h; lo[j] = bf16_rn(v[j] - bf16_f(h));
            }
            int bo = (row * (BK * 2) + kq * 2) ^ ((row & 7) << 4);
            *(u16x4*)((char*)Ahi + bo) = hi;
            *(u16x4*)((char*)Alo + bo) = lo;
        }
        // ---- stage B (gate rows then up rows) ----
#pragma unroll
        for (int it = 0; it < 8; ++it) {
            int idx = it * 256 + tid;          // 0..2047
            int mat = idx >> 10;               // 0 gate, 1 up
            int row = (idx >> 4) & 63;
            int kq = (idx & 15) << 2;
            const float* src = (mat == 0 ? gbase : ubase) + (size_t)row * DM + kt * BK + kq;
            f32x4 v = *(const f32x4*)src;
            u16x4 hi, lo;
#pragma unroll
            for (int j = 0; j < 4; ++j) {
                unsigned short h = bf16_rn(v[j]);
                hi[j] = h; lo[j] = bf16_rn(v[j] - bf16_f(h));
            }
            int bo = mat * (BN * BK * 2) + ((row * (BK * 2) + kq * 2) ^ ((row & 7) << 4));
            *(u16x4*)((char*)Bhi + bo) = hi;
            *(u16x4*)((char*)Blo + bo) = lo;
        }
        __syncthreads();
        // ---- MFMA ----
#pragma unroll
        for (int ks = 0; ks < 2; ++ks) {
            const int kb = (ks * 32 + lk * 8) * 2;
            bf16x8 ah[4], al[4];
#pragma unroll
            for (int mf = 0; mf < 4; ++mf) {
                int row = wm * 64 + mf * 16 + lr;
                int bo = (row * (BK * 2) + kb) ^ ((row & 7) << 4);
                ah[mf] = *(bf16x8*)((char*)Ahi + bo);
                al[mf] = *(bf16x8*)((char*)Alo + bo);
            }
            bf16x8 bgh[2], bgl[2], buh[2], bul[2];
#pragma unroll
            for (int nf = 0; nf < 2; ++nf) {
                int col = wn * 32 + nf * 16 + lr;
                int bo = (col * (BK * 2) + kb) ^ ((col & 7) << 4);
                bgh[nf] = *(bf16x8*)((char*)Bhi + bo);
                bgl[nf] = *(bf16x8*)((char*)Blo + bo);
                buh[nf] = *(bf16x8*)((char*)Bhi + BN * BK * 2 + bo);
                bul[nf] = *(bf16x8*)((char*)Blo + BN * BK * 2 + bo);
            }
#pragma unroll
            for (int mf = 0; mf < 4; ++mf)
#pragma unroll
                for (int nf = 0; nf < 2; ++nf) {
                    accg[mf][nf] = MFMA(ah[mf], bgh[nf], accg[mf][nf]);
                    accg[mf][nf] = MFMA(ah[mf], bgl[nf], accg[mf][nf]);
                    accg[mf][nf] = MFMA(al[mf], bgh[nf], accg[mf][nf]);
                    accu[mf][nf] = MFMA(ah[mf], buh[nf], accu[mf][nf]);
                    accu[mf][nf] = MFMA(ah[mf], bul[nf], accu[mf][nf]);
                    accu[mf][nf] = MFMA(al[mf], buh[nf], accu[mf][nf]);
                }
        }
        __syncthreads();
    }
    // ---- epilogue: h = silu(g)*u -> H hi/lo ----
    const int hrow0 = offs[e] + mb * BM;
#pragma unroll
    for (int mf = 0; mf < 4; ++mf)
#pragma unroll
        for (int nf = 0; nf < 2; ++nf)
#pragma unroll
            for (int j = 0; j < 4; ++j) {
                int r = wm * 64 + mf * 16 + lk * 4 + j;
                if (mb * BM + r < ne) {
                    int c = wn * 32 + nf * 16 + lr;
                    float g = accg[mf][nf][j], u = accu[mf][nf][j];
                    float h = (g / (1.f + expf(-g))) * u;
                    unsigned short hh = bf16_rn(h);
                    unsigned short hl = bf16_rn(h - bf16_f(hh));
                    size_t o = (size_t)(hrow0 + r) * CH + (size_t)(by * BN + c);
                    Hhi[o] = hh; Hlo[o] = hl;
                }
            }
}

// ---------------------------------------------------------------------------
// Kernel B: partial Y = H_chunk . dw[:, chunk]^T, scaled by router weight,
// atomicAdd scatter into out (exactly 2 expert contributions per element).
// ---------------------------------------------------------------------------
__global__ __launch_bounds__(256) void down_kernel(
    const float* __restrict__ dw,
    const int* __restrict__ counts, const int* __restrict__ offs,
    const int* __restrict__ tok_list, const float* __restrict__ w_list,
    const unsigned short* __restrict__ Hhi, const unsigned short* __restrict__ Hlo,
    float* __restrict__ out, int cb, int CH)
{
    const int e = blockIdx.x / MBMAX, mb = blockIdx.x % MBMAX;
    const int ne = counts[e];
    if (mb * BM >= ne) return;
    const int by = blockIdx.y;          // d_model 64-col block (0..15)
    const int tid = threadIdx.x;

    __shared__ unsigned short Ahi[BM * BK], Alo[BM * BK];
    __shared__ unsigned short Bhi[BN * BK], Blo[BN * BK];

    const int lane = tid & 63, wv = tid >> 6;
    const int wm = wv >> 1, wn = wv & 1;
    const int lr = lane & 15, lk = lane >> 4;

    f32x4 acc[4][2];
#pragma unroll
    for (int m = 0; m < 4; ++m)
#pragma unroll
        for (int n = 0; n < 2; ++n) acc[m][n] = (f32x4)0.f;

    const int hrow0 = offs[e] + mb * BM;
    const float* dbase = dw + (size_t)e * DM * DI + (size_t)(by * BN) * DI + cb;
    const int nkt = CH / BK;

    for (int kt = 0; kt < nkt; ++kt) {
        // ---- stage A from H (already bf16 hi/lo) ----
#pragma unroll
        for (int it = 0; it < 4; ++it) {
            int idx = it * 256 + tid;          // 0..1023
            int row = idx >> 3;                // 0..127
            int k8 = (idx & 7) << 3;           // 0,8,..,56
            u16x8 vh = (u16x8)0, vl = (u16x8)0;
            if (mb * BM + row < ne) {
                size_t o = (size_t)(hrow0 + row) * CH + (size_t)(kt * BK + k8);
                vh = *(const u16x8*)(Hhi + o);
                vl = *(const u16x8*)(Hlo + o);
            }
            int bo = (row * (BK * 2) + k8 * 2) ^ ((row & 7) << 4);
            *(u16x8*)((char*)Ahi + bo) = vh;
            *(u16x8*)((char*)Alo + bo) = vl;
        }
        // ---- stage B from down_w f32 ----
#pragma unroll
        for (int it = 0; it < 4; ++it) {
            int idx = it * 256 + tid;          // 0..1023
            int row = idx >> 4;                // 0..63
            int kq = (idx & 15) << 2;
            f32x4 v = *(const f32x4*)(dbase + (size_t)row * DI + kt * BK + kq);
            u16x4 hi, lo;
#pragma unroll
            for (int j = 0; j < 4; ++j) {
                unsigned short h = bf16_rn(v[j]);
                hi[j] = h; lo[j] = bf16_rn(v[j] - bf16_f(h));
            }
            int bo = (row * (BK * 2) + kq * 2) ^ ((row & 7) << 4);
            *(u16x4*)((char*)Bhi + bo) = hi;
            *(u16x4*)((char*)Blo + bo) = lo;
        }
        __syncthreads();
#pragma unroll
        for (int ks = 0; ks < 2; ++ks) {
            const int kb = (ks * 32 + lk * 8) * 2;
            bf16x8 ah[4], al[4];
#pragma unroll
            for (int mf = 0; mf < 4; ++mf) {
                int row = wm * 64 + mf * 16 + lr;
                int bo = (row * (BK * 2) + kb) ^ ((row & 7) << 4);
                ah[mf] = *(bf16x8*)((char*)Ahi + bo);
                al[mf] = *(bf16x8*)((char*)Alo + bo);
            }
            bf16x8 bh[2], bl[2];
#pragma unroll
            for (int nf = 0; nf < 2; ++nf) {
                int col = wn * 32 + nf * 16 + lr;
                int bo = (col * (BK * 2) + kb) ^ ((col & 7) << 4);
                bh[nf] = *(bf16x8*)((char*)Bhi + bo);
                bl[nf] = *(bf16x8*)((char*)Blo + bo);
            }
#pragma unroll
            for (int mf = 0; mf < 4; ++mf)
#pragma unroll
                for (int nf = 0; nf < 2; ++nf) {
                    acc[mf][nf] = MFMA(ah[mf], bh[nf], acc[mf][nf]);
                    acc[mf][nf] = MFMA(ah[mf], bl[nf], acc[mf][nf]);
                    acc[mf][nf] = MFMA(al[mf], bh[nf], acc[mf][nf]);
                }
        }
        __syncthreads();
    }
    // ---- epilogue: weighted scatter-add ----
#pragma unroll
    for (int mf = 0; mf < 4; ++mf)
#pragma unroll
        for (int j = 0; j < 4; ++j) {
            int r = wm * 64 + mf * 16 + lk * 4 + j;
            if (mb * BM + r < ne) {
                int t = tok_list[e * MAXPE + mb * BM + r];
                float w = w_list[e * MAXPE + mb * BM + r];
#pragma unroll
                for (int nf = 0; nf < 2; ++nf) {
                    int c = by * BN + wn * 32 + nf * 16 + lr;
                    atomicAdd(&out[(size_t)t * DM + c], w * acc[mf][nf][j]);
                }
            }
        }
}

// ---------------------------------------------------------------------------
extern "C" void kernel_launch(void* const* d_in, const int* in_sizes, int n_in,
                              void* d_out, int out_size, void* d_ws, size_t ws_size,
                              hipStream_t stream) {
    const float* x = (const float*)d_in[0];
    const float* router_w = (const float*)d_in[1];
    const float* router_b = (const float*)d_in[2];
    const float* gate_w = (const float*)d_in[3];
    const float* up_w = (const float*)d_in[4];
    const float* down_w = (const float*)d_in[5];
    float* out = (float*)d_out;

    char* ws = (char*)d_ws;
    int* counts = (int*)ws;                                   // 8 ints
    int* offs = (int*)(ws + 64);                              // 8 ints
    int* tok_list = (int*)(ws + 128);                         // 8*8192 ints
    float* w_list = (float*)(ws + 128 + NE * MAXPE * 4);      // 8*8192 floats
    size_t hbase = 128 + (size_t)NE * MAXPE * 8;
    hbase = (hbase + 255) & ~(size_t)255;

    // Largest d_inner chunk whose H (hi+lo bf16, 16384 rows) fits in ws.
    int CH = 128;
    for (int c = DI; c >= 128; c >>= 1) {
        if (hbase + (size_t)2 * TOK * c * 4 <= ws_size) { CH = c; break; }
    }
    unsigned short* Hhi = (unsigned short*)(ws + hbase);
    unsigned short* Hlo = Hhi + (size_t)2 * TOK * CH;

    hipMemsetAsync(d_out, 0, (size_t)out_size * sizeof(float), stream);
    hipMemsetAsync(counts, 0, NE * sizeof(int), stream);

    router_kernel<<<TOK / 4, 256, 0, stream>>>(x, router_w, router_b,
                                               counts, tok_list, w_list);
    scan_kernel<<<1, 64, 0, stream>>>(counts, offs);

    for (int cb = 0; cb < DI; cb += CH) {
        gateup_kernel<<<dim3(NE * MBMAX, CH / BN), 256, 0, stream>>>(
            x, gate_w, up_w, counts, offs, tok_list, Hhi, Hlo, cb, CH);
        down_kernel<<<dim3(NE * MBMAX, DM / BN), 256, 0, stream>>>(
            down_w, counts, offs, tok_list, w_list, Hhi, Hlo, out, cb, CH);
    }
}

// Round 2
// 1637.258 us; speedup vs baseline: 2.6394x; 2.6394x over previous
//
#include <hip/hip_runtime.h>

// MoE FFN top-2/8. R2: pure-bf16 MFMA GEMMs (m97 structure, global_load_lds
// staging), weights/X pre-converted to bf16 once per launch, full-width H.

#define DM 1024
#define DI 4096
#define NE 8
#define TOK 8192
#define MAXPE 8192
#define BM 128
#define BK 64
#define MBMAX (MAXPE / BM)   // 64

typedef __attribute__((ext_vector_type(4))) float f32x4;
typedef __attribute__((ext_vector_type(8))) short bf16x8;
typedef __attribute__((ext_vector_type(8))) unsigned short u16x8;

#define MFMA(a, b, c) __builtin_amdgcn_mfma_f32_16x16x32_bf16(a, b, c, 0, 0, 0)
#define GLDS16(g, l) __builtin_amdgcn_global_load_lds( \
    (const __attribute__((address_space(1))) unsigned int*)(g), \
    (__attribute__((address_space(3))) unsigned int*)(l), 16, 0, 0)

__device__ __forceinline__ unsigned short bf16_rn(float f) {
    unsigned int u = __builtin_bit_cast(unsigned int, f);
    u += 0x7fffu + ((u >> 16) & 1u);
    return (unsigned short)(u >> 16);
}

// ---------------------------------------------------------------------------
// Router (identical numerics to R1 — it passed; don't perturb top-2 ties).
// ---------------------------------------------------------------------------
__global__ __launch_bounds__(256) void router_kernel(
    const float* __restrict__ x, const float* __restrict__ rw,
    const float* __restrict__ rb,
    int* __restrict__ counts, int* __restrict__ tok_list,
    float* __restrict__ w_list)
{
    int t = blockIdx.x * 4 + (threadIdx.x >> 6);
    int lane = threadIdx.x & 63;
    const float* xr = x + (size_t)t * DM;
    float acc[NE];
#pragma unroll
    for (int e = 0; e < NE; ++e) acc[e] = 0.f;
    for (int i = lane; i < DM; i += 64) {
        float xv = xr[i];
#pragma unroll
        for (int e = 0; e < NE; ++e) acc[e] += xv * rw[e * DM + i];
    }
#pragma unroll
    for (int e = 0; e < NE; ++e) {
        float v = acc[e];
#pragma unroll
        for (int s = 32; s >= 1; s >>= 1) v += __shfl_xor(v, s, 64);
        acc[e] = v;
    }
    if (lane == 0) {
        float l0 = -3.4e38f, l1 = -3.4e38f;
        int i0 = 0, i1 = 0;
#pragma unroll
        for (int e = 0; e < NE; ++e) {
            float v = acc[e] + rb[e];
            if (v > l0) { l1 = l0; i1 = i0; l0 = v; i0 = e; }
            else if (v > l1) { l1 = v; i1 = e; }
        }
        float z = expf(l1 - l0);
        float w0 = 1.f / (1.f + z);
        float w1 = z / (1.f + z);
        int p0 = atomicAdd(&counts[i0], 1);
        tok_list[i0 * MAXPE + p0] = t; w_list[i0 * MAXPE + p0] = w0;
        int p1 = atomicAdd(&counts[i1], 1);
        tok_list[i1 * MAXPE + p1] = t; w_list[i1 * MAXPE + p1] = w1;
    }
}

__global__ void scan_kernel(const int* __restrict__ counts, int* __restrict__ offs) {
    if (threadIdx.x == 0) {
        int s = 0;
        for (int e = 0; e < NE; ++e) { offs[e] = s; s += counts[e]; }
    }
}

// ---------------------------------------------------------------------------
// f32 -> bf16 conversion, 8 elems/thread, optional per-"expert" source stride.
// dst is contiguous; src element = src + (i8>>shift)*estride + (i8 & ((1<<shift)-1)).
// ---------------------------------------------------------------------------
__global__ __launch_bounds__(256) void conv_kernel(
    const float* __restrict__ src, unsigned short* __restrict__ dst,
    long total, int shift, long estride)
{
    long i8 = ((long)blockIdx.x * 256 + threadIdx.x) * 8;
    if (i8 >= total) return;
    long e = i8 >> shift;
    long r = i8 - (e << shift);
    const float* s = src + e * estride + r;
    f32x4 a = *(const f32x4*)s;
    f32x4 b = *(const f32x4*)(s + 4);
    u16x8 o;
#pragma unroll
    for (int j = 0; j < 4; ++j) { o[j] = bf16_rn(a[j]); o[4 + j] = bf16_rn(b[j]); }
    *(u16x8*)(dst + i8) = o;
}

// ---------------------------------------------------------------------------
// Gate+Up GEMM: 128 tokens x (64 cols gate + 64 cols up), BK=64, 4 waves,
// global_load_lds staging from pre-converted bf16. Epilogue silu(g)*u -> H.
// ---------------------------------------------------------------------------
__global__ __launch_bounds__(256) void gateup2(
    const unsigned short* __restrict__ xb,
    const unsigned short* __restrict__ gwb,   // [NE][CHC][DM] slice
    const unsigned short* __restrict__ uwb,
    const int* __restrict__ counts, const int* __restrict__ offs,
    const int* __restrict__ tok_list,
    unsigned short* __restrict__ H, int cb, int CHC)
{
    const int e = blockIdx.x >> 6, mb = blockIdx.x & 63;
    const int ne = counts[e];
    if (mb * BM >= ne) return;
    const int by = blockIdx.y;
    const int tid = threadIdx.x;
    const int lane = tid & 63, w = tid >> 6;
    const int lr = lane & 15, lk = lane >> 4;
    const int lrow = lane >> 3;            // 0..7 within a 1KB wave-load
    const int lcol = (lane & 7) * 8;       // bf16 col within BK

    __shared__ unsigned short As[BM * BK];   // 16KB
    __shared__ unsigned short Bg[64 * BK];   // 8KB
    __shared__ unsigned short Bu[64 * BK];   // 8KB

    size_t srcA[4];
#pragma unroll
    for (int i = 0; i < 4; ++i) {
        int rg = mb * BM + w * 32 + i * 8 + lrow;
        int rc = rg < ne ? rg : ne - 1;        // clamp tail -> finite data
        int tok = tok_list[e * MAXPE + rc];
        srcA[i] = (size_t)tok * DM + lcol;
    }
    size_t srcB[2];
#pragma unroll
    for (int i = 0; i < 2; ++i) {
        int row = by * 64 + w * 16 + i * 8 + lrow;
        srcB[i] = ((size_t)e * CHC + row) * DM + lcol;
    }

    const int wm = w >> 1, wn = w & 1;
    f32x4 accg[4][2], accu[4][2];
#pragma unroll
    for (int m = 0; m < 4; ++m)
#pragma unroll
        for (int n = 0; n < 2; ++n) { accg[m][n] = (f32x4)0.f; accu[m][n] = (f32x4)0.f; }

    for (int kt = 0; kt < DM / BK; ++kt) {
        const int kb = kt * BK;
#pragma unroll
        for (int i = 0; i < 4; ++i)
            GLDS16(xb + srcA[i] + kb, As + (w * 32 + i * 8) * BK);
#pragma unroll
        for (int i = 0; i < 2; ++i) {
            GLDS16(gwb + srcB[i] + kb, Bg + (w * 16 + i * 8) * BK);
            GLDS16(uwb + srcB[i] + kb, Bu + (w * 16 + i * 8) * BK);
        }
        __syncthreads();
#pragma unroll
        for (int ks = 0; ks < 2; ++ks) {
            const int ko = ks * 32 + lk * 8;
            bf16x8 a[4], bg[2], bu[2];
#pragma unroll
            for (int mf = 0; mf < 4; ++mf)
                a[mf] = *(const bf16x8*)&As[(wm * 64 + mf * 16 + lr) * BK + ko];
#pragma unroll
            for (int nf = 0; nf < 2; ++nf) {
                bg[nf] = *(const bf16x8*)&Bg[(wn * 32 + nf * 16 + lr) * BK + ko];
                bu[nf] = *(const bf16x8*)&Bu[(wn * 32 + nf * 16 + lr) * BK + ko];
            }
#pragma unroll
            for (int mf = 0; mf < 4; ++mf)
#pragma unroll
                for (int nf = 0; nf < 2; ++nf) {
                    accg[mf][nf] = MFMA(a[mf], bg[nf], accg[mf][nf]);
                    accu[mf][nf] = MFMA(a[mf], bu[nf], accu[mf][nf]);
                }
        }
        __syncthreads();
    }

    const int hrow0 = offs[e] + mb * BM;
#pragma unroll
    for (int mf = 0; mf < 4; ++mf)
#pragma unroll
        for (int nf = 0; nf < 2; ++nf)
#pragma unroll
            for (int j = 0; j < 4; ++j) {
                int r = wm * 64 + mf * 16 + lk * 4 + j;
                if (mb * BM + r < ne) {
                    int c = cb + by * 64 + wn * 32 + nf * 16 + lr;
                    float g = accg[mf][nf][j], u = accu[mf][nf][j];
                    float h = (g / (1.f + expf(-g))) * u;
                    H[(size_t)(hrow0 + r) * DI + c] = bf16_rn(h);
                }
            }
}

// ---------------------------------------------------------------------------
// Down GEMM: 128 H-rows x 128 out-cols, K=DI in one pass. Weighted atomicAdd.
// ---------------------------------------------------------------------------
__global__ __launch_bounds__(256) void down2(
    const unsigned short* __restrict__ dwb,   // [NE][DM][DI]
    const int* __restrict__ counts, const int* __restrict__ offs,
    const int* __restrict__ tok_list, const float* __restrict__ w_list,
    const unsigned short* __restrict__ H,
    float* __restrict__ out)
{
    const int e = blockIdx.x >> 6, mb = blockIdx.x & 63;
    const int ne = counts[e];
    if (mb * BM >= ne) return;
    const int by = blockIdx.y;                // 0..7 (128-col group of DM)
    const int tid = threadIdx.x;
    const int lane = tid & 63, w = tid >> 6;
    const int lr = lane & 15, lk = lane >> 4;
    const int lrow = lane >> 3;
    const int lcol = (lane & 7) * 8;

    __shared__ unsigned short As[BM * BK];    // 16KB
    __shared__ unsigned short Bs[BM * BK];    // 16KB

    const int hrow0 = offs[e] + mb * BM;
    size_t srcA[4], srcB[4];
#pragma unroll
    for (int i = 0; i < 4; ++i) {
        srcA[i] = (size_t)(hrow0 + w * 32 + i * 8 + lrow) * DI + lcol;
        srcB[i] = ((size_t)e * DM + by * 128 + w * 32 + i * 8 + lrow) * DI + lcol;
    }

    const int wm = w >> 1, wn = w & 1;
    f32x4 acc[4][4];
#pragma unroll
    for (int m = 0; m < 4; ++m)
#pragma unroll
        for (int n = 0; n < 4; ++n) acc[m][n] = (f32x4)0.f;

    for (int kt = 0; kt < DI / BK; ++kt) {
        const int kb = kt * BK;
#pragma unroll
        for (int i = 0; i < 4; ++i)
            GLDS16(H + srcA[i] + kb, As + (w * 32 + i * 8) * BK);
#pragma unroll
        for (int i = 0; i < 4; ++i)
            GLDS16(dwb + srcB[i] + kb, Bs + (w * 32 + i * 8) * BK);
        __syncthreads();
#pragma unroll
        for (int ks = 0; ks < 2; ++ks) {
            const int ko = ks * 32 + lk * 8;
            bf16x8 a[4], b[4];
#pragma unroll
            for (int mf = 0; mf < 4; ++mf)
                a[mf] = *(const bf16x8*)&As[(wm * 64 + mf * 16 + lr) * BK + ko];
#pragma unroll
            for (int nf = 0; nf < 4; ++nf)
                b[nf] = *(const bf16x8*)&Bs[(wn * 64 + nf * 16 + lr) * BK + ko];
#pragma unroll
            for (int mf = 0; mf < 4; ++mf)
#pragma unroll
                for (int nf = 0; nf < 4; ++nf)
                    acc[mf][nf] = MFMA(a[mf], b[nf], acc[mf][nf]);
        }
        __syncthreads();
    }

#pragma unroll
    for (int mf = 0; mf < 4; ++mf)
#pragma unroll
        for (int j = 0; j < 4; ++j) {
            int r = wm * 64 + mf * 16 + lk * 4 + j;
            int row = mb * BM + r;
            if (row < ne) {
                int t = tok_list[e * MAXPE + row];
                float wgt = w_list[e * MAXPE + row];
#pragma unroll
                for (int nf = 0; nf < 4; ++nf) {
                    int c = by * 128 + wn * 64 + nf * 16 + lr;
                    atomicAdd(&out[(size_t)t * DM + c], wgt * acc[mf][nf][j]);
                }
            }
        }
}

// ---------------------------------------------------------------------------
extern "C" void kernel_launch(void* const* d_in, const int* in_sizes, int n_in,
                              void* d_out, int out_size, void* d_ws, size_t ws_size,
                              hipStream_t stream) {
    const float* x = (const float*)d_in[0];
    const float* router_w = (const float*)d_in[1];
    const float* router_b = (const float*)d_in[2];
    const float* gate_w = (const float*)d_in[3];
    const float* up_w = (const float*)d_in[4];
    const float* down_w = (const float*)d_in[5];
    float* out = (float*)d_out;

    char* ws = (char*)d_ws;
    int* counts = (int*)ws;
    int* offs = (int*)(ws + 64);
    int* tok_list = (int*)(ws + 128);
    float* w_list = (float*)(ws + 128 + (size_t)NE * MAXPE * 4);
    size_t off = 128 + (size_t)NE * MAXPE * 8;
    off = (off + 255) & ~(size_t)255;

    unsigned short* xb = (unsigned short*)(ws + off);  off += (size_t)TOK * DM * 2;
    unsigned short* dwb = (unsigned short*)(ws + off); off += (size_t)NE * DM * DI * 2;
    unsigned short* H = (unsigned short*)(ws + off);   off += (size_t)(2 * TOK + BM) * DI * 2;

    int CHC = 64;
    for (int c = 2048; c >= 64; c >>= 1)
        if (off + (size_t)2 * NE * c * DM * 2 <= ws_size) { CHC = c; break; }
    unsigned short* gwb = (unsigned short*)(ws + off);
    unsigned short* uwb = gwb + (size_t)NE * CHC * DM;

    hipMemsetAsync(out, 0, (size_t)out_size * sizeof(float), stream);
    hipMemsetAsync(counts, 0, NE * sizeof(int), stream);

    router_kernel<<<TOK / 4, 256, 0, stream>>>(x, router_w, router_b,
                                               counts, tok_list, w_list);
    scan_kernel<<<1, 64, 0, stream>>>(counts, offs);

    // x -> bf16 (contiguous: shift covers whole range so e==0)
    conv_kernel<<<(TOK * DM) / 2048, 256, 0, stream>>>(
        x, xb, (long)TOK * DM, 23, 0);
    // down_w -> bf16 (contiguous, 2^25 elements)
    conv_kernel<<<(int)(((long)NE * DM * DI) / 2048), 256, 0, stream>>>(
        down_w, dwb, (long)NE * DM * DI, 25, 0);

    const int sh = 10 + __builtin_ctz((unsigned)CHC);   // log2(CHC*DM)
    for (int cb = 0; cb < DI; cb += CHC) {
        long tot = (long)NE * CHC * DM;
        conv_kernel<<<(int)(tot / 2048), 256, 0, stream>>>(
            gate_w + (size_t)cb * DM, gwb, tot, sh, (long)DI * DM);
        conv_kernel<<<(int)(tot / 2048), 256, 0, stream>>>(
            up_w + (size_t)cb * DM, uwb, tot, sh, (long)DI * DM);
        gateup2<<<dim3(NE * MBMAX, CHC / 64), 256, 0, stream>>>(
            xb, gwb, uwb, counts, offs, tok_list, H, cb, CHC);
    }
    down2<<<dim3(NE * MBMAX, DM / 128), 256, 0, stream>>>(
        dwb, counts, offs, tok_list, w_list, H, out);
}

// Round 3
// 1098.308 us; speedup vs baseline: 3.9345x; 1.4907x over previous
//
#include <hip/hip_runtime.h>

// MoE FFN top-2/8. R3: bf16 MFMA GEMMs with double-buffered prefetch
// (T3-minimum 2-phase), pre-swizzled-source LDS (T2 via m173: linear LDS dest
// for global_load_lds, XOR-permuted global column + XOR on ds_read), and
// XCD-aware block swizzle (expert -> XCD).

#define DM 1024
#define DI 4096
#define NE 8
#define TOK 8192
#define MAXPE 8192
#define BM 128
#define BK 64
#define MBMAX (MAXPE / BM)   // 64

typedef __attribute__((ext_vector_type(4))) float f32x4;
typedef __attribute__((ext_vector_type(8))) short bf16x8;
typedef __attribute__((ext_vector_type(8))) unsigned short u16x8;

#define MFMA(a, b, c) __builtin_amdgcn_mfma_f32_16x16x32_bf16(a, b, c, 0, 0, 0)
#define GLDS16(g, l) __builtin_amdgcn_global_load_lds( \
    (const __attribute__((address_space(1))) unsigned int*)(g), \
    (__attribute__((address_space(3))) unsigned int*)(l), 16, 0, 0)

__device__ __forceinline__ unsigned short bf16_rn(float f) {
    unsigned int u = __builtin_bit_cast(unsigned int, f);
    u += 0x7fffu + ((u >> 16) & 1u);
    return (unsigned short)(u >> 16);
}

// ---------------------------------------------------------------------------
// Router (unchanged — numerics must not move).
// ---------------------------------------------------------------------------
__global__ __launch_bounds__(256) void router_kernel(
    const float* __restrict__ x, const float* __restrict__ rw,
    const float* __restrict__ rb,
    int* __restrict__ counts, int* __restrict__ tok_list,
    float* __restrict__ w_list)
{
    int t = blockIdx.x * 4 + (threadIdx.x >> 6);
    int lane = threadIdx.x & 63;
    const float* xr = x + (size_t)t * DM;
    float acc[NE];
#pragma unroll
    for (int e = 0; e < NE; ++e) acc[e] = 0.f;
    for (int i = lane; i < DM; i += 64) {
        float xv = xr[i];
#pragma unroll
        for (int e = 0; e < NE; ++e) acc[e] += xv * rw[e * DM + i];
    }
#pragma unroll
    for (int e = 0; e < NE; ++e) {
        float v = acc[e];
#pragma unroll
        for (int s = 32; s >= 1; s >>= 1) v += __shfl_xor(v, s, 64);
        acc[e] = v;
    }
    if (lane == 0) {
        float l0 = -3.4e38f, l1 = -3.4e38f;
        int i0 = 0, i1 = 0;
#pragma unroll
        for (int e = 0; e < NE; ++e) {
            float v = acc[e] + rb[e];
            if (v > l0) { l1 = l0; i1 = i0; l0 = v; i0 = e; }
            else if (v > l1) { l1 = v; i1 = e; }
        }
        float z = expf(l1 - l0);
        float w0 = 1.f / (1.f + z);
        float w1 = z / (1.f + z);
        int p0 = atomicAdd(&counts[i0], 1);
        tok_list[i0 * MAXPE + p0] = t; w_list[i0 * MAXPE + p0] = w0;
        int p1 = atomicAdd(&counts[i1], 1);
        tok_list[i1 * MAXPE + p1] = t; w_list[i1 * MAXPE + p1] = w1;
    }
}

__global__ void scan_kernel(const int* __restrict__ counts, int* __restrict__ offs) {
    if (threadIdx.x == 0) {
        int s = 0;
        for (int e = 0; e < NE; ++e) { offs[e] = s; s += counts[e]; }
    }
}

// ---------------------------------------------------------------------------
// f32 -> bf16 conversion, 8 elems/thread, optional per-expert source stride.
// ---------------------------------------------------------------------------
__global__ __launch_bounds__(256) void conv_kernel(
    const float* __restrict__ src, unsigned short* __restrict__ dst,
    long total, int shift, long estride)
{
    long i8 = ((long)blockIdx.x * 256 + threadIdx.x) * 8;
    if (i8 >= total) return;
    long e = i8 >> shift;
    long r = i8 - (e << shift);
    const float* s = src + e * estride + r;
    f32x4 a = *(const f32x4*)s;
    f32x4 b = *(const f32x4*)(s + 4);
    u16x8 o;
#pragma unroll
    for (int j = 0; j < 4; ++j) { o[j] = bf16_rn(a[j]); o[4 + j] = bf16_rn(b[j]); }
    *(u16x8*)(dst + i8) = o;
}

// ---------------------------------------------------------------------------
// Gate+Up GEMM: 128 tokens x (64 gate + 64 up cols), BK=64, 4 waves.
// Double-buffered global_load_lds prefetch; pre-swizzled source columns.
// ---------------------------------------------------------------------------
__global__ __launch_bounds__(256) void gateup2(
    const unsigned short* __restrict__ xb,
    const unsigned short* __restrict__ gwb,   // [NE][CHC][DM] slice
    const unsigned short* __restrict__ uwb,
    const int* __restrict__ counts, const int* __restrict__ offs,
    const int* __restrict__ tok_list,
    unsigned short* __restrict__ H, int cb, int CHC)
{
    const int bxs = (((int)blockIdx.x & 7) << 6) | ((int)blockIdx.x >> 3); // XCD swizzle
    const int e = bxs >> 6, mb = bxs & 63;
    const int ne = counts[e];
    if (mb * BM >= ne) return;
    const int by = blockIdx.y;
    const int tid = threadIdx.x;
    const int lane = tid & 63, w = tid >> 6;
    const int lr = lane & 15, lk = lane >> 4;
    const int lrow = lane >> 3;                       // lds row within 8-row group
    const int lcol = (((lane & 7) ^ lrow) << 3);      // pre-swizzled source col (elems)

    __shared__ __align__(16) unsigned short As[2][BM * BK];   // 2 x 16KB
    __shared__ __align__(16) unsigned short Bg[2][64 * BK];   // 2 x 8KB
    __shared__ __align__(16) unsigned short Bu[2][64 * BK];   // 2 x 8KB

    size_t srcA[4];
#pragma unroll
    for (int i = 0; i < 4; ++i) {
        int rg = mb * BM + w * 32 + i * 8 + lrow;
        int rc = rg < ne ? rg : ne - 1;               // clamp tail -> finite data
        int tok = tok_list[e * MAXPE + rc];
        srcA[i] = (size_t)tok * DM + lcol;
    }
    size_t srcB[2];
#pragma unroll
    for (int i = 0; i < 2; ++i) {
        int row = by * 64 + w * 16 + i * 8 + lrow;
        srcB[i] = ((size_t)e * CHC + row) * DM + lcol;
    }

    const int wm = w >> 1, wn = w & 1;
    const int xsw = (lr & 7) << 4;                    // read-side XOR (bytes)
    f32x4 accg[4][2], accu[4][2];
#pragma unroll
    for (int m = 0; m < 4; ++m)
#pragma unroll
        for (int n = 0; n < 2; ++n) { accg[m][n] = (f32x4)0.f; accu[m][n] = (f32x4)0.f; }

    // prologue: stage K-tile 0 into buf 0
#pragma unroll
    for (int i = 0; i < 4; ++i)
        GLDS16(xb + srcA[i], &As[0][(w * 32 + i * 8) * BK]);
#pragma unroll
    for (int i = 0; i < 2; ++i) {
        GLDS16(gwb + srcB[i], &Bg[0][(w * 16 + i * 8) * BK]);
        GLDS16(uwb + srcB[i], &Bu[0][(w * 16 + i * 8) * BK]);
    }
    __syncthreads();

    const int NKT = DM / BK;
#pragma unroll 2
    for (int kt = 0; kt < NKT; ++kt) {
        const int cur = kt & 1;
        // prefetch next tile into other buffer (hidden under compute below)
        if (kt + 1 < NKT) {
            const int nkb = (kt + 1) * BK;
#pragma unroll
            for (int i = 0; i < 4; ++i)
                GLDS16(xb + srcA[i] + nkb, &As[cur ^ 1][(w * 32 + i * 8) * BK]);
#pragma unroll
            for (int i = 0; i < 2; ++i) {
                GLDS16(gwb + srcB[i] + nkb, &Bg[cur ^ 1][(w * 16 + i * 8) * BK]);
                GLDS16(uwb + srcB[i] + nkb, &Bu[cur ^ 1][(w * 16 + i * 8) * BK]);
            }
        }
        // compute current buffer
#pragma unroll
        for (int ks = 0; ks < 2; ++ks) {
            const int kbyte = (ks * 64 + lk * 16) ^ xsw;
            bf16x8 a[4], bg[2], bu[2];
#pragma unroll
            for (int mf = 0; mf < 4; ++mf)
                a[mf] = *(const bf16x8*)((const char*)As[cur] +
                         (wm * 64 + mf * 16 + lr) * 128 + kbyte);
#pragma unroll
            for (int nf = 0; nf < 2; ++nf) {
                bg[nf] = *(const bf16x8*)((const char*)Bg[cur] +
                          (wn * 32 + nf * 16 + lr) * 128 + kbyte);
                bu[nf] = *(const bf16x8*)((const char*)Bu[cur] +
                          (wn * 32 + nf * 16 + lr) * 128 + kbyte);
            }
#pragma unroll
            for (int mf = 0; mf < 4; ++mf)
#pragma unroll
                for (int nf = 0; nf < 2; ++nf) {
                    accg[mf][nf] = MFMA(a[mf], bg[nf], accg[mf][nf]);
                    accu[mf][nf] = MFMA(a[mf], bu[nf], accu[mf][nf]);
                }
        }
        __syncthreads();   // single per-tile barrier: drains next-tile stage
    }

    const int hrow0 = offs[e] + mb * BM;
#pragma unroll
    for (int mf = 0; mf < 4; ++mf)
#pragma unroll
        for (int nf = 0; nf < 2; ++nf)
#pragma unroll
            for (int j = 0; j < 4; ++j) {
                int r = wm * 64 + mf * 16 + lk * 4 + j;
                if (mb * BM + r < ne) {
                    int c = cb + by * 64 + wn * 32 + nf * 16 + lr;
                    float g = accg[mf][nf][j], u = accu[mf][nf][j];
                    float h = (g / (1.f + expf(-g))) * u;
                    H[(size_t)(hrow0 + r) * DI + c] = bf16_rn(h);
                }
            }
}

// ---------------------------------------------------------------------------
// Down GEMM: 128 H-rows x 128 out-cols, K=DI. Same pipeline structure.
// ---------------------------------------------------------------------------
__global__ __launch_bounds__(256) void down2(
    const unsigned short* __restrict__ dwb,   // [NE][DM][DI] bf16
    const int* __restrict__ counts, const int* __restrict__ offs,
    const int* __restrict__ tok_list, const float* __restrict__ w_list,
    const unsigned short* __restrict__ H,
    float* __restrict__ out)
{
    const int bxs = (((int)blockIdx.x & 7) << 6) | ((int)blockIdx.x >> 3); // XCD swizzle
    const int e = bxs >> 6, mb = bxs & 63;
    const int ne = counts[e];
    if (mb * BM >= ne) return;
    const int by = blockIdx.y;                // 0..7 (128-col group of DM)
    const int tid = threadIdx.x;
    const int lane = tid & 63, w = tid >> 6;
    const int lr = lane & 15, lk = lane >> 4;
    const int lrow = lane >> 3;
    const int lcol = (((lane & 7) ^ lrow) << 3);

    __shared__ __align__(16) unsigned short As[2][BM * BK];   // 2 x 16KB
    __shared__ __align__(16) unsigned short Bs[2][BM * BK];   // 2 x 16KB

    const int hrow0 = offs[e] + mb * BM;
    size_t srcA[4], srcB[4];
#pragma unroll
    for (int i = 0; i < 4; ++i) {
        srcA[i] = (size_t)(hrow0 + w * 32 + i * 8 + lrow) * DI + lcol;
        srcB[i] = ((size_t)e * DM + by * 128 + w * 32 + i * 8 + lrow) * DI + lcol;
    }

    const int wm = w >> 1, wn = w & 1;
    const int xsw = (lr & 7) << 4;
    f32x4 acc[4][4];
#pragma unroll
    for (int m = 0; m < 4; ++m)
#pragma unroll
        for (int n = 0; n < 4; ++n) acc[m][n] = (f32x4)0.f;

    // prologue
#pragma unroll
    for (int i = 0; i < 4; ++i) {
        GLDS16(H + srcA[i], &As[0][(w * 32 + i * 8) * BK]);
        GLDS16(dwb + srcB[i], &Bs[0][(w * 32 + i * 8) * BK]);
    }
    __syncthreads();

    const int NKT = DI / BK;
#pragma unroll 2
    for (int kt = 0; kt < NKT; ++kt) {
        const int cur = kt & 1;
        if (kt + 1 < NKT) {
            const int nkb = (kt + 1) * BK;
#pragma unroll
            for (int i = 0; i < 4; ++i) {
                GLDS16(H + srcA[i] + nkb, &As[cur ^ 1][(w * 32 + i * 8) * BK]);
                GLDS16(dwb + srcB[i] + nkb, &Bs[cur ^ 1][(w * 32 + i * 8) * BK]);
            }
        }
#pragma unroll
        for (int ks = 0; ks < 2; ++ks) {
            const int kbyte = (ks * 64 + lk * 16) ^ xsw;
            bf16x8 a[4], b[4];
#pragma unroll
            for (int mf = 0; mf < 4; ++mf)
                a[mf] = *(const bf16x8*)((const char*)As[cur] +
                         (wm * 64 + mf * 16 + lr) * 128 + kbyte);
#pragma unroll
            for (int nf = 0; nf < 4; ++nf)
                b[nf] = *(const bf16x8*)((const char*)Bs[cur] +
                         (wn * 64 + nf * 16 + lr) * 128 + kbyte);
#pragma unroll
            for (int mf = 0; mf < 4; ++mf)
#pragma unroll
                for (int nf = 0; nf < 4; ++nf)
                    acc[mf][nf] = MFMA(a[mf], b[nf], acc[mf][nf]);
        }
        __syncthreads();
    }

#pragma unroll
    for (int mf = 0; mf < 4; ++mf)
#pragma unroll
        for (int j = 0; j < 4; ++j) {
            int r = wm * 64 + mf * 16 + lk * 4 + j;
            int row = mb * BM + r;
            if (row < ne) {
                int t = tok_list[e * MAXPE + row];
                float wgt = w_list[e * MAXPE + row];
#pragma unroll
                for (int nf = 0; nf < 4; ++nf) {
                    int c = by * 128 + wn * 64 + nf * 16 + lr;
                    atomicAdd(&out[(size_t)t * DM + c], wgt * acc[mf][nf][j]);
                }
            }
        }
}

// ---------------------------------------------------------------------------
extern "C" void kernel_launch(void* const* d_in, const int* in_sizes, int n_in,
                              void* d_out, int out_size, void* d_ws, size_t ws_size,
                              hipStream_t stream) {
    const float* x = (const float*)d_in[0];
    const float* router_w = (const float*)d_in[1];
    const float* router_b = (const float*)d_in[2];
    const float* gate_w = (const float*)d_in[3];
    const float* up_w = (const float*)d_in[4];
    const float* down_w = (const float*)d_in[5];
    float* out = (float*)d_out;

    char* ws = (char*)d_ws;
    int* counts = (int*)ws;
    int* offs = (int*)(ws + 64);
    int* tok_list = (int*)(ws + 128);
    float* w_list = (float*)(ws + 128 + (size_t)NE * MAXPE * 4);
    size_t off = 128 + (size_t)NE * MAXPE * 8;
    off = (off + 255) & ~(size_t)255;

    unsigned short* xb = (unsigned short*)(ws + off);  off += (size_t)TOK * DM * 2;
    unsigned short* dwb = (unsigned short*)(ws + off); off += (size_t)NE * DM * DI * 2;
    unsigned short* H = (unsigned short*)(ws + off);   off += (size_t)(2 * TOK + BM) * DI * 2;

    int CHC = 64;
    for (int c = 2048; c >= 64; c >>= 1)
        if (off + (size_t)2 * NE * c * DM * 2 <= ws_size) { CHC = c; break; }
    unsigned short* gwb = (unsigned short*)(ws + off);
    unsigned short* uwb = gwb + (size_t)NE * CHC * DM;

    hipMemsetAsync(out, 0, (size_t)out_size * sizeof(float), stream);
    hipMemsetAsync(counts, 0, NE * sizeof(int), stream);

    router_kernel<<<TOK / 4, 256, 0, stream>>>(x, router_w, router_b,
                                               counts, tok_list, w_list);
    scan_kernel<<<1, 64, 0, stream>>>(counts, offs);

    conv_kernel<<<(TOK * DM) / 2048, 256, 0, stream>>>(
        x, xb, (long)TOK * DM, 23, 0);
    conv_kernel<<<(int)(((long)NE * DM * DI) / 2048), 256, 0, stream>>>(
        down_w, dwb, (long)NE * DM * DI, 25, 0);

    const int sh = 10 + __builtin_ctz((unsigned)CHC);   // log2(CHC*DM)
    for (int cb = 0; cb < DI; cb += CHC) {
        long tot = (long)NE * CHC * DM;
        conv_kernel<<<(int)(tot / 2048), 256, 0, stream>>>(
            gate_w + (size_t)cb * DM, gwb, tot, sh, (long)DI * DM);
        conv_kernel<<<(int)(tot / 2048), 256, 0, stream>>>(
            up_w + (size_t)cb * DM, uwb, tot, sh, (long)DI * DM);
        gateup2<<<dim3(NE * MBMAX, CHC / 64), 256, 0, stream>>>(
            xb, gwb, uwb, counts, offs, tok_list, H, cb, CHC);
    }
    down2<<<dim3(NE * MBMAX, DM / 128), 256, 0, stream>>>(
        dwb, counts, offs, tok_list, w_list, H, out);
}

// Round 4
// 903.367 us; speedup vs baseline: 4.7836x; 1.2158x over previous
//
#include <hip/hip_runtime.h>

// MoE FFN top-2/8. R4: compacted tile grid (device-built tile table, no dud
// blocks), single-buffered 32KB LDS m97-structure GEMMs (4 blocks/CU TLP),
// pre-swizzled-source LDS (bank-conflict-free), pure bf16 MFMA.

#define DM 1024
#define DI 4096
#define NE 8
#define TOK 8192
#define MAXPE 8192
#define BM 128
#define BK 64
#define NTILES 136           // >= sum ceil(ne/128) = 135 worst case

typedef __attribute__((ext_vector_type(4))) float f32x4;
typedef __attribute__((ext_vector_type(8))) short bf16x8;
typedef __attribute__((ext_vector_type(8))) unsigned short u16x8;

#define MFMA(a, b, c) __builtin_amdgcn_mfma_f32_16x16x32_bf16(a, b, c, 0, 0, 0)
#define GLDS16(g, l) __builtin_amdgcn_global_load_lds( \
    (const __attribute__((address_space(1))) unsigned int*)(g), \
    (__attribute__((address_space(3))) unsigned int*)(l), 16, 0, 0)

__device__ __forceinline__ unsigned short bf16_rn(float f) {
    unsigned int u = __builtin_bit_cast(unsigned int, f);
    u += 0x7fffu + ((u >> 16) & 1u);
    return (unsigned short)(u >> 16);
}

// ---------------------------------------------------------------------------
// Router (numerics unchanged since R1).
// ---------------------------------------------------------------------------
__global__ __launch_bounds__(256) void router_kernel(
    const float* __restrict__ x, const float* __restrict__ rw,
    const float* __restrict__ rb,
    int* __restrict__ counts, int* __restrict__ tok_list,
    float* __restrict__ w_list)
{
    int t = blockIdx.x * 4 + (threadIdx.x >> 6);
    int lane = threadIdx.x & 63;
    const float* xr = x + (size_t)t * DM;
    float acc[NE];
#pragma unroll
    for (int e = 0; e < NE; ++e) acc[e] = 0.f;
    for (int i = lane; i < DM; i += 64) {
        float xv = xr[i];
#pragma unroll
        for (int e = 0; e < NE; ++e) acc[e] += xv * rw[e * DM + i];
    }
#pragma unroll
    for (int e = 0; e < NE; ++e) {
        float v = acc[e];
#pragma unroll
        for (int s = 32; s >= 1; s >>= 1) v += __shfl_xor(v, s, 64);
        acc[e] = v;
    }
    if (lane == 0) {
        float l0 = -3.4e38f, l1 = -3.4e38f;
        int i0 = 0, i1 = 0;
#pragma unroll
        for (int e = 0; e < NE; ++e) {
            float v = acc[e] + rb[e];
            if (v > l0) { l1 = l0; i1 = i0; l0 = v; i0 = e; }
            else if (v > l1) { l1 = v; i1 = e; }
        }
        float z = expf(l1 - l0);
        float w0 = 1.f / (1.f + z);
        float w1 = z / (1.f + z);
        int p0 = atomicAdd(&counts[i0], 1);
        tok_list[i0 * MAXPE + p0] = t; w_list[i0 * MAXPE + p0] = w0;
        int p1 = atomicAdd(&counts[i1], 1);
        tok_list[i1 * MAXPE + p1] = t; w_list[i1 * MAXPE + p1] = w1;
    }
}

// Prefix offsets + compact (expert, mb) tile table. Sentinel -1 pads to NTILES.
__global__ void scan_kernel(const int* __restrict__ counts,
                            int* __restrict__ offs, int* __restrict__ tiles) {
    if (threadIdx.x == 0) {
        int s = 0, nt = 0;
        for (int e = 0; e < NE; ++e) { offs[e] = s; s += counts[e]; }
        for (int e = 0; e < NE; ++e) {
            int nmb = (counts[e] + BM - 1) / BM;
            for (int mb = 0; mb < nmb && nt < NTILES; ++mb)
                tiles[nt++] = (e << 16) | mb;
        }
        for (; nt < NTILES; ++nt) tiles[nt] = -1;
    }
}

// ---------------------------------------------------------------------------
// f32 -> bf16 conversion, 8 elems/thread, optional per-expert source stride.
// ---------------------------------------------------------------------------
__global__ __launch_bounds__(256) void conv_kernel(
    const float* __restrict__ src, unsigned short* __restrict__ dst,
    long total, int shift, long estride)
{
    long i8 = ((long)blockIdx.x * 256 + threadIdx.x) * 8;
    if (i8 >= total) return;
    long e = i8 >> shift;
    long r = i8 - (e << shift);
    const float* s = src + e * estride + r;
    f32x4 a = *(const f32x4*)s;
    f32x4 b = *(const f32x4*)(s + 4);
    u16x8 o;
#pragma unroll
    for (int j = 0; j < 4; ++j) { o[j] = bf16_rn(a[j]); o[4 + j] = bf16_rn(b[j]); }
    *(u16x8*)(dst + i8) = o;
}

// ---------------------------------------------------------------------------
// Gate+Up GEMM: 128 tokens x (64 gate + 64 up cols), BK=64, 4 waves,
// single-buffer 32KB LDS (m97 structure), pre-swizzled source columns.
// ---------------------------------------------------------------------------
__global__ __launch_bounds__(256, 4) void gateup3(
    const unsigned short* __restrict__ xb,
    const unsigned short* __restrict__ gwb,   // [NE][CHC][DM] slice
    const unsigned short* __restrict__ uwb,
    const int* __restrict__ counts, const int* __restrict__ offs,
    const int* __restrict__ tiles, const int* __restrict__ tok_list,
    unsigned short* __restrict__ H, int cb, int CHC)
{
    const int pk = tiles[blockIdx.x];
    if (pk < 0) return;
    const int e = pk >> 16, mb = pk & 0xffff;
    const int ne = counts[e];
    const int by = blockIdx.y;
    const int tid = threadIdx.x;
    const int lane = tid & 63, w = tid >> 6;
    const int lr = lane & 15, lk = lane >> 4;
    const int lrow = lane >> 3;                       // lds row within 8-row group
    const int lcol = (((lane & 7) ^ lrow) << 3);      // pre-swizzled source col

    __shared__ __align__(16) unsigned short As[BM * BK];   // 16KB
    __shared__ __align__(16) unsigned short Bg[64 * BK];   // 8KB
    __shared__ __align__(16) unsigned short Bu[64 * BK];   // 8KB

    size_t srcA[4];
#pragma unroll
    for (int i = 0; i < 4; ++i) {
        int rg = mb * BM + w * 32 + i * 8 + lrow;
        int rc = rg < ne ? rg : ne - 1;               // clamp tail -> finite data
        int tok = tok_list[e * MAXPE + rc];
        srcA[i] = (size_t)tok * DM + lcol;
    }
    size_t srcB[2];
#pragma unroll
    for (int i = 0; i < 2; ++i) {
        int row = by * 64 + w * 16 + i * 8 + lrow;
        srcB[i] = ((size_t)e * CHC + row) * DM + lcol;
    }

    const int wm = w >> 1, wn = w & 1;
    const int xsw = (lr & 7) << 4;                    // read-side XOR (bytes)
    f32x4 accg[4][2], accu[4][2];
#pragma unroll
    for (int m = 0; m < 4; ++m)
#pragma unroll
        for (int n = 0; n < 2; ++n) { accg[m][n] = (f32x4)0.f; accu[m][n] = (f32x4)0.f; }

    for (int kt = 0; kt < DM / BK; ++kt) {
        const int kb = kt * BK;
#pragma unroll
        for (int i = 0; i < 4; ++i)
            GLDS16(xb + srcA[i] + kb, &As[(w * 32 + i * 8) * BK]);
#pragma unroll
        for (int i = 0; i < 2; ++i) {
            GLDS16(gwb + srcB[i] + kb, &Bg[(w * 16 + i * 8) * BK]);
            GLDS16(uwb + srcB[i] + kb, &Bu[(w * 16 + i * 8) * BK]);
        }
        __syncthreads();
#pragma unroll
        for (int ks = 0; ks < 2; ++ks) {
            const int kbyte = (ks * 64 + lk * 16) ^ xsw;
            bf16x8 a[4], bg[2], bu[2];
#pragma unroll
            for (int mf = 0; mf < 4; ++mf)
                a[mf] = *(const bf16x8*)((const char*)As +
                         (wm * 64 + mf * 16 + lr) * 128 + kbyte);
#pragma unroll
            for (int nf = 0; nf < 2; ++nf) {
                bg[nf] = *(const bf16x8*)((const char*)Bg +
                          (wn * 32 + nf * 16 + lr) * 128 + kbyte);
                bu[nf] = *(const bf16x8*)((const char*)Bu +
                          (wn * 32 + nf * 16 + lr) * 128 + kbyte);
            }
#pragma unroll
            for (int mf = 0; mf < 4; ++mf)
#pragma unroll
                for (int nf = 0; nf < 2; ++nf) {
                    accg[mf][nf] = MFMA(a[mf], bg[nf], accg[mf][nf]);
                    accu[mf][nf] = MFMA(a[mf], bu[nf], accu[mf][nf]);
                }
        }
        __syncthreads();
    }

    const int hrow0 = offs[e] + mb * BM;
#pragma unroll
    for (int mf = 0; mf < 4; ++mf)
#pragma unroll
        for (int nf = 0; nf < 2; ++nf)
#pragma unroll
            for (int j = 0; j < 4; ++j) {
                int r = wm * 64 + mf * 16 + lk * 4 + j;
                if (mb * BM + r < ne) {
                    int c = cb + by * 64 + wn * 32 + nf * 16 + lr;
                    float g = accg[mf][nf][j], u = accu[mf][nf][j];
                    float h = (g / (1.f + expf(-g))) * u;
                    H[(size_t)(hrow0 + r) * DI + c] = bf16_rn(h);
                }
            }
}

// ---------------------------------------------------------------------------
// Down GEMM: 128 H-rows x 128 out-cols, K=DI, single-buffer 32KB LDS.
// ---------------------------------------------------------------------------
__global__ __launch_bounds__(256, 4) void down3(
    const unsigned short* __restrict__ dwb,   // [NE][DM][DI] bf16
    const int* __restrict__ counts, const int* __restrict__ offs,
    const int* __restrict__ tiles, const int* __restrict__ tok_list,
    const float* __restrict__ w_list,
    const unsigned short* __restrict__ H,
    float* __restrict__ out)
{
    const int pk = tiles[blockIdx.x];
    if (pk < 0) return;
    const int e = pk >> 16, mb = pk & 0xffff;
    const int ne = counts[e];
    const int by = blockIdx.y;                // 0..7 (128-col group of DM)
    const int tid = threadIdx.x;
    const int lane = tid & 63, w = tid >> 6;
    const int lr = lane & 15, lk = lane >> 4;
    const int lrow = lane >> 3;
    const int lcol = (((lane & 7) ^ lrow) << 3);

    __shared__ __align__(16) unsigned short As[BM * BK];    // 16KB
    __shared__ __align__(16) unsigned short Bs[BM * BK];    // 16KB

    const int hrow0 = offs[e] + mb * BM;
    size_t srcA[4], srcB[4];
#pragma unroll
    for (int i = 0; i < 4; ++i) {
        srcA[i] = (size_t)(hrow0 + w * 32 + i * 8 + lrow) * DI + lcol;
        srcB[i] = ((size_t)e * DM + by * 128 + w * 32 + i * 8 + lrow) * DI + lcol;
    }

    const int wm = w >> 1, wn = w & 1;
    const int xsw = (lr & 7) << 4;
    f32x4 acc[4][4];
#pragma unroll
    for (int m = 0; m < 4; ++m)
#pragma unroll
        for (int n = 0; n < 4; ++n) acc[m][n] = (f32x4)0.f;

    for (int kt = 0; kt < DI / BK; ++kt) {
        const int kb = kt * BK;
#pragma unroll
        for (int i = 0; i < 4; ++i) {
            GLDS16(H + srcA[i] + kb, &As[(w * 32 + i * 8) * BK]);
            GLDS16(dwb + srcB[i] + kb, &Bs[(w * 32 + i * 8) * BK]);
        }
        __syncthreads();
#pragma unroll
        for (int ks = 0; ks < 2; ++ks) {
            const int kbyte = (ks * 64 + lk * 16) ^ xsw;
            bf16x8 a[4], b[4];
#pragma unroll
            for (int mf = 0; mf < 4; ++mf)
                a[mf] = *(const bf16x8*)((const char*)As +
                         (wm * 64 + mf * 16 + lr) * 128 + kbyte);
#pragma unroll
            for (int nf = 0; nf < 4; ++nf)
                b[nf] = *(const bf16x8*)((const char*)Bs +
                         (wn * 64 + nf * 16 + lr) * 128 + kbyte);
#pragma unroll
            for (int mf = 0; mf < 4; ++mf)
#pragma unroll
                for (int nf = 0; nf < 4; ++nf)
                    acc[mf][nf] = MFMA(a[mf], b[nf], acc[mf][nf]);
        }
        __syncthreads();
    }

#pragma unroll
    for (int mf = 0; mf < 4; ++mf)
#pragma unroll
        for (int j = 0; j < 4; ++j) {
            int r = wm * 64 + mf * 16 + lk * 4 + j;
            int row = mb * BM + r;
            if (row < ne) {
                int t = tok_list[e * MAXPE + row];
                float wgt = w_list[e * MAXPE + row];
#pragma unroll
                for (int nf = 0; nf < 4; ++nf) {
                    int c = by * 128 + wn * 64 + nf * 16 + lr;
                    atomicAdd(&out[(size_t)t * DM + c], wgt * acc[mf][nf][j]);
                }
            }
        }
}

// ---------------------------------------------------------------------------
extern "C" void kernel_launch(void* const* d_in, const int* in_sizes, int n_in,
                              void* d_out, int out_size, void* d_ws, size_t ws_size,
                              hipStream_t stream) {
    const float* x = (const float*)d_in[0];
    const float* router_w = (const float*)d_in[1];
    const float* router_b = (const float*)d_in[2];
    const float* gate_w = (const float*)d_in[3];
    const float* up_w = (const float*)d_in[4];
    const float* down_w = (const float*)d_in[5];
    float* out = (float*)d_out;

    char* ws = (char*)d_ws;
    int* counts = (int*)ws;                              // +0
    int* offs = (int*)(ws + 64);                         // +64
    int* tiles = (int*)(ws + 128);                       // +128 (136 ints)
    int* tok_list = (int*)(ws + 768);
    float* w_list = (float*)(ws + 768 + (size_t)NE * MAXPE * 4);
    size_t off = 768 + (size_t)NE * MAXPE * 8;
    off = (off + 255) & ~(size_t)255;

    unsigned short* xb = (unsigned short*)(ws + off);  off += (size_t)TOK * DM * 2;
    unsigned short* dwb = (unsigned short*)(ws + off); off += (size_t)NE * DM * DI * 2;
    unsigned short* H = (unsigned short*)(ws + off);   off += (size_t)(2 * TOK + BM) * DI * 2;

    int CHC = 64;
    for (int c = 2048; c >= 64; c >>= 1)
        if (off + (size_t)2 * NE * c * DM * 2 <= ws_size) { CHC = c; break; }
    unsigned short* gwb = (unsigned short*)(ws + off);
    unsigned short* uwb = gwb + (size_t)NE * CHC * DM;

    hipMemsetAsync(out, 0, (size_t)out_size * sizeof(float), stream);
    hipMemsetAsync(counts, 0, NE * sizeof(int), stream);

    router_kernel<<<TOK / 4, 256, 0, stream>>>(x, router_w, router_b,
                                               counts, tok_list, w_list);
    scan_kernel<<<1, 64, 0, stream>>>(counts, offs, tiles);

    conv_kernel<<<(TOK * DM) / 2048, 256, 0, stream>>>(
        x, xb, (long)TOK * DM, 23, 0);
    conv_kernel<<<(int)(((long)NE * DM * DI) / 2048), 256, 0, stream>>>(
        down_w, dwb, (long)NE * DM * DI, 25, 0);

    const int sh = 10 + __builtin_ctz((unsigned)CHC);   // log2(CHC*DM)
    for (int cb = 0; cb < DI; cb += CHC) {
        long tot = (long)NE * CHC * DM;
        conv_kernel<<<(int)(tot / 2048), 256, 0, stream>>>(
            gate_w + (size_t)cb * DM, gwb, tot, sh, (long)DI * DM);
        conv_kernel<<<(int)(tot / 2048), 256, 0, stream>>>(
            up_w + (size_t)cb * DM, uwb, tot, sh, (long)DI * DM);
        gateup3<<<dim3(NTILES, CHC / 64), 256, 0, stream>>>(
            xb, gwb, uwb, counts, offs, tiles, tok_list, H, cb, CHC);
    }
    down3<<<dim3(NTILES, DM / 128), 256, 0, stream>>>(
        dwb, counts, offs, tiles, tok_list, w_list, H, out);
}